// Round 13
// baseline (33.053 us; speedup 1.0000x reference)
//
#include <hip/hip_runtime.h>
#include <stdint.h>

// Problem: x (4096,2048) int32 {0,1}; references (1024,2048) f32 {0,1};
// out (4096,1024) f32 = (hamming - 1024) / (0.5*sqrt(2048)).
// Identity: s=1-2x, t=1-2r in {+-1}: hamming = (2048 - s.t)/2 ->
//   out[b,d] = -(inv_std/2) * dot_pm1(b,d)     (exact integer dot)
// fp4 E2M1: +1=0x2, -1=0xA; MX scales all 1.0 (E8M0 0x7F) -> exact f32 dot.
constexpr int B_ROWS = 4096;
constexpr int D_ROWS = 1024;
constexpr int L_LEN  = 2048;

constexpr int MBLKS = B_ROWS / 32;    // 128 row-blocks of 32
constexpr int NBLKS = D_ROWS / 32;    // 32
constexpr int KCH   = L_LEN / 64;     // 32 K-chunks of 64 elems

// Fragment-contiguous layout (verified exact on-device in R11/R12 via LDS):
// 16-B slot s = (blk*KCH + kc)*64 + lane, lane = (khalf<<5) | row-in-block;
// slot holds elems k = kc*64 + khalf*32 + [0..31] of row blk*32+(lane&31),
// low nibble first. A wave's MFMA operand = slots [base .. base+63] = 1 KB
// CONTIGUOUS -> one coalesced global_load_dwordx4 per operand. No LDS needed.
constexpr int A_DWORDS = MBLKS * KCH * 64 * 4;   // 1048576 (4 MiB)
constexpr int B_DWORDS = NBLKS * KCH * 64 * 4;   //  262144 (1 MiB)

using int32x4 = __attribute__((ext_vector_type(4))) int;
using int32x8 = __attribute__((ext_vector_type(8))) int;
using f32x16  = __attribute__((ext_vector_type(16))) float;

// ---------------------------------------------------------------------------
// Kernel 1: convert inputs to +-1 fp4 directly in fragment layout.
// One thread per output dword (8 elems of one row). Writes: 64 consecutive
// dwords/wave = 256 B contiguous (perfect). Reads: 4-thread runs of 128
// contiguous B (2 full lines), row-hopping -- line-efficient, 40 MB once.
// ---------------------------------------------------------------------------
__global__ __launch_bounds__(256) void convert_frag_kernel(
    const int* __restrict__ x, const float* __restrict__ r,
    uint32_t* __restrict__ Af, uint32_t* __restrict__ Bf)
{
  const int tid = blockIdx.x * blockDim.x + threadIdx.x;
  const int nth = gridDim.x * blockDim.x;
  for (int dw = tid; dw < A_DWORDS + B_DWORDS; dw += nth) {
    if (dw < A_DWORDS) {
      const int slot = dw >> 2, q = dw & 3;
      const int lane = slot & 63, kc = (slot >> 6) & (KCH - 1);
      const int mblk = slot >> 11;
      const int row  = mblk * 32 + (lane & 31);
      const int k0   = kc * 64 + (lane >> 5) * 32 + q * 8;
      const int* s = x + (size_t)row * L_LEN + k0;
      const int4 v0 = *reinterpret_cast<const int4*>(s);
      const int4 v1 = *reinterpret_cast<const int4*>(s + 4);
      uint32_t wo;
      wo  = (v0.x ? 0xAu : 0x2u);
      wo |= (v0.y ? 0xAu : 0x2u) << 4;
      wo |= (v0.z ? 0xAu : 0x2u) << 8;
      wo |= (v0.w ? 0xAu : 0x2u) << 12;
      wo |= (v1.x ? 0xAu : 0x2u) << 16;
      wo |= (v1.y ? 0xAu : 0x2u) << 20;
      wo |= (v1.z ? 0xAu : 0x2u) << 24;
      wo |= (v1.w ? 0xAu : 0x2u) << 28;
      Af[dw] = wo;
    } else {
      const int dwb  = dw - A_DWORDS;
      const int slot = dwb >> 2, q = dwb & 3;
      const int lane = slot & 63, kc = (slot >> 6) & (KCH - 1);
      const int nblk = slot >> 11;
      const int row  = nblk * 32 + (lane & 31);
      const int k0   = kc * 64 + (lane >> 5) * 32 + q * 8;
      const float* s = r + (size_t)row * L_LEN + k0;
      const float4 v0 = *reinterpret_cast<const float4*>(s);
      const float4 v1 = *reinterpret_cast<const float4*>(s + 4);
      uint32_t wo;
      wo  = (v0.x != 0.0f ? 0xAu : 0x2u);
      wo |= (v0.y != 0.0f ? 0xAu : 0x2u) << 4;
      wo |= (v0.z != 0.0f ? 0xAu : 0x2u) << 8;
      wo |= (v0.w != 0.0f ? 0xAu : 0x2u) << 12;
      wo |= (v1.x != 0.0f ? 0xAu : 0x2u) << 16;
      wo |= (v1.y != 0.0f ? 0xAu : 0x2u) << 20;
      wo |= (v1.z != 0.0f ? 0xAu : 0x2u) << 24;
      wo |= (v1.w != 0.0f ? 0xAu : 0x2u) << 28;
      Bf[dwb] = wo;
    }
  }
}

// ---------------------------------------------------------------------------
// Kernel 2: MX-fp4 GEMM, NO LDS, NO BARRIERS. Operands pre-laid-out in
// fragment order -> per (kc, operand): one coalesced 1 KB dwordx4 load from
// L2 straight into the MFMA registers. Waves fully independent; compiler
// software-pipelines loads across MFMAs (m114 implicit overlap), unroll 4.
//   Block: 512 threads = 8 waves (4m x 2n), wave tile 64x32 (2 MFMAs/kc).
//   Grid: 256 blocks (16 mtiles x 16 ntiles), XCD-chunked bijective swizzle;
//   per-XCD chunk: 2 A-mtile streams (512 KB) + all B (1 MB) -> L2-resident.
//   Pipes: A 64 MB + B 16 MB from L2 ~2.3 us, MFMA 1.9 us, out 16 MB ~2.5 us.
// ---------------------------------------------------------------------------
constexpr int NWG = 256;

__global__ __launch_bounds__(512, 2) void gemm_fp4_kernel(
    const int32x4* __restrict__ Af, const int32x4* __restrict__ Bf,
    float* __restrict__ out)
{
  const int lin = blockIdx.x;
  const int swz = (lin & 7) * (NWG / 8) + (lin >> 3);   // bijective, 256%8==0
  const int mtile = swz >> 4;    // ntile fast within an XCD chunk
  const int ntile = swz & 15;

  const int t    = threadIdx.x;
  const int lane = t & 63;
  const int w    = t >> 6;       // 0..7
  const int wm   = w >> 1;       // 0..3: 64-row m-slice
  const int wn   = w & 1;        // 0..1: 32-col n-slice

  const int mblk0 = mtile * 8 + wm * 2;   // wave covers mblk0, mblk0+1
  const int nblk  = ntile * 2 + wn;

  const int32x4* pA0 = Af + (size_t)(mblk0    ) * KCH * 64 + lane;
  const int32x4* pA1 = Af + (size_t)(mblk0 + 1) * KCH * 64 + lane;
  const int32x4* pB  = Bf + (size_t) nblk       * KCH * 64 + lane;

  f32x16 acc0 = {}, acc1 = {};

#pragma unroll 4
  for (int kc = 0; kc < KCH; ++kc) {
    const int32x4 b4 = pB [kc * 64];
    const int32x4 a0 = pA0[kc * 64];
    const int32x4 a1 = pA1[kc * 64];
    const int32x8 b8  = {b4[0], b4[1], b4[2], b4[3], 0, 0, 0, 0};
    const int32x8 a80 = {a0[0], a0[1], a0[2], a0[3], 0, 0, 0, 0};
    const int32x8 a81 = {a1[0], a1[1], a1[2], a1[3], 0, 0, 0, 0};
    // fmt 4/4 = FP4; scales = E8M0 1.0 (0x7F), opsel 0.
    acc0 = __builtin_amdgcn_mfma_scale_f32_32x32x64_f8f6f4(
        a80, b8, acc0, 4, 4, 0, 0x7F7F7F7F, 0, 0x7F7F7F7F);
    acc1 = __builtin_amdgcn_mfma_scale_f32_32x32x64_f8f6f4(
        a81, b8, acc1, 4, 4, 0, 0x7F7F7F7F, 0, 0x7F7F7F7F);
  }

  // Epilogue: verified 32x32 C/D layout: col = lane&31,
  // row = (reg&3) + 8*(reg>>2) + 4*(lane>>5).
  const float scale = -0.5f * 0.04419417382415922f;
  const int col = nblk * 32 + (lane & 31);
#pragma unroll
  for (int reg = 0; reg < 16; ++reg) {
    const int rin = (reg & 3) + 8 * (reg >> 2) + 4 * (lane >> 5);
    out[(size_t)(mblk0 * 32 + rin)       * D_ROWS + col] = acc0[reg] * scale;
    out[(size_t)((mblk0 + 1) * 32 + rin) * D_ROWS + col] = acc1[reg] * scale;
  }
}

extern "C" void kernel_launch(void* const* d_in, const int* in_sizes, int n_in,
                              void* d_out, int out_size, void* d_ws, size_t ws_size,
                              hipStream_t stream) {
  const int*   x = (const int*)d_in[0];     // (4096, 2048) int32
  const float* r = (const float*)d_in[1];   // (1024, 2048) float32
  float*     out = (float*)d_out;           // (4096, 1024) float32

  uint32_t* Af = (uint32_t*)d_ws;                 // 4 MiB fragment-layout A
  uint32_t* Bf = Af + A_DWORDS;                   // 1 MiB fragment-layout B

  convert_frag_kernel<<<2048, 256, 0, stream>>>(x, r, Af, Bf);

  gemm_fp4_kernel<<<NWG, 512, 0, stream>>>(
      (const int32x4*)Af, (const int32x4*)Bf, out);
}